// Round 5
// baseline (3624.767 us; speedup 1.0000x reference)
//
#include <hip/hip_runtime.h>

// B=256 samples, D=2048 dims, N=16384 bank rows. Dominant cost:
// sims = normalize(inputs) @ features^T / 0.05 -> per-row logsumexp.
// HBM floor: features 134 MB f32 read once ~= 21 us at 6.3 TB/s.
// GEMM design: B (the HBM stream) staged f32 into LDS via global_load_lds
// (deep queue, no VGPRs), 4 buffers, counted vmcnt(10) -- never drained in
// the loop. A (1 MB bf16, L2-hot) read per-wave direct to regs, 2-deep.
// f32->bf16 at fragment read via v_cvt_pk_bf16_f32.

constexpr int Bn = 256;     // batch
constexpr int Dk = 2048;    // feature dim
constexpr int Nn = 16384;   // bank rows
constexpr int NKT = 32;     // K-steps (BK = 64 f32)
constexpr int NPB = 512;    // partial chunks (256 nb * 2 wn)
constexpr float TEMP_INV = 20.0f;

typedef float f32x4 __attribute__((ext_vector_type(4)));
typedef short s16x8 __attribute__((ext_vector_type(8)));

__device__ inline unsigned short f2bf(float f) {
  union { float f; unsigned u; } v; v.f = f;
  unsigned r = v.u + 0x7FFFu + ((v.u >> 16) & 1u);   // RNE
  return (unsigned short)(r >> 16);
}

// 8 f32 -> 8 bf16 packed, RNE, via v_cvt_pk_bf16_f32 (no builtin on gfx950)
__device__ inline s16x8 cvt8(float4 a, float4 b) {
  union { unsigned int u[4]; s16x8 v; } r;
  asm("v_cvt_pk_bf16_f32 %0, %1, %2" : "=v"(r.u[0]) : "v"(a.x), "v"(a.y));
  asm("v_cvt_pk_bf16_f32 %0, %1, %2" : "=v"(r.u[1]) : "v"(a.z), "v"(a.w));
  asm("v_cvt_pk_bf16_f32 %0, %1, %2" : "=v"(r.u[2]) : "v"(b.x), "v"(b.y));
  asm("v_cvt_pk_bf16_f32 %0, %1, %2" : "=v"(r.u[3]) : "v"(b.z), "v"(b.w));
  return r.v;
}

// ---------------- kernel 1: normalize inputs -> bf16 + exact s_own ----------
__global__ __launch_bounds__(256) void norm_sown_kernel(
    const float* __restrict__ x, const float* __restrict__ feats,
    const int* __restrict__ targets, unsigned short* __restrict__ xb,
    float* __restrict__ s_own) {
  int row = blockIdx.x, t = threadIdx.x;
  const float* xr = x + (size_t)row * Dk;
  const float* fr = feats + (size_t)targets[row] * Dk;
  float4 a  = *(const float4*)(xr + t * 8);
  float4 b  = *(const float4*)(xr + t * 8 + 4);
  float4 fa = *(const float4*)(fr + t * 8);
  float4 fb = *(const float4*)(fr + t * 8 + 4);
  float ss = a.x*a.x + a.y*a.y + a.z*a.z + a.w*a.w
           + b.x*b.x + b.y*b.y + b.z*b.z + b.w*b.w;
  float dt = a.x*fa.x + a.y*fa.y + a.z*fa.z + a.w*fa.w
           + b.x*fb.x + b.y*fb.y + b.z*fb.z + b.w*fb.w;
  #pragma unroll
  for (int d = 1; d < 64; d <<= 1) {
    ss += __shfl_xor(ss, d, 64);
    dt += __shfl_xor(dt, d, 64);
  }
  __shared__ float rs[4], rd[4];
  if ((t & 63) == 0) { rs[t >> 6] = ss; rd[t >> 6] = dt; }
  __syncthreads();
  float inv = rsqrtf(rs[0] + rs[1] + rs[2] + rs[3]);
  union { unsigned short s[8]; uint4 v; } pk;
  pk.s[0] = f2bf(a.x*inv); pk.s[1] = f2bf(a.y*inv);
  pk.s[2] = f2bf(a.z*inv); pk.s[3] = f2bf(a.w*inv);
  pk.s[4] = f2bf(b.x*inv); pk.s[5] = f2bf(b.y*inv);
  pk.s[6] = f2bf(b.z*inv); pk.s[7] = f2bf(b.w*inv);
  *(uint4*)(xb + (size_t)row * Dk + t * 8) = pk.v;
  if (t == 0) s_own[row] = (rd[0] + rd[1] + rd[2] + rd[3]) * inv * TEMP_INV;
}

// ---------------- kernel 2: B-in-LDS pipelined GEMM + partial LSE -----------
// grid 512: mb = bid>>8 (128 rows), nb = bid&255 (64 cols). 512 thr, 8 waves:
// wm in [0,4) -> 32 rows, wn in [0,2) -> 32 cols.
__global__ __launch_bounds__(512, 4) void gemm_kernel(
    const unsigned short* __restrict__ xb, const float* __restrict__ feats,
    float* __restrict__ pmax, float* __restrict__ psum) {
  __shared__ float Bs[4][64 * 64];   // 4 x 16 KB f32 tiles

  int tid = threadIdx.x;
  int w = tid >> 6, lane = tid & 63;
  int wm = w >> 1, wn = w & 1;
  int bid = blockIdx.x;
  int mb = bid >> 8, nb = bid & 255;
  int n0 = nb * 64;
  int lr = lane & 15, q = lane >> 4;

  // ---- B staging: slot s = w*2+j covers LDS rows s*4+q, 16B pos lr.
  // Stored pos p holds global granule g = p ^ (row&7)  (inverse == same XOR).
  auto stage_B = [&](int kt, int buf) {
    int k0 = kt * 64;
    #pragma unroll
    for (int j = 0; j < 2; ++j) {
      int s = w * 2 + j;
      int row = s * 4 + q;
      int g = lr ^ (row & 7);
      const float* src = feats + (size_t)(n0 + row) * Dk + k0 + g * 4;
      __builtin_amdgcn_global_load_lds(
          (const __attribute__((address_space(1))) unsigned int*)src,
          (__attribute__((address_space(3))) unsigned int*)
              ((unsigned char*)&Bs[buf][0] + s * 1024),
          16, 0, 0);
    }
  };

  // ---- A: direct global fragment loads (L1/L2-hot xb), 2-deep ----
  const unsigned short* aptr[2];
  #pragma unroll
  for (int mt = 0; mt < 2; ++mt)
    aptr[mt] = xb + (size_t)(mb * 128 + wm * 32 + mt * 16 + lr) * Dk + q * 8;

  s16x8 Af[2][2][2];   // [parity][ks][mt]
  auto load_A = [&](int t, int par) {
    #pragma unroll
    for (int ks = 0; ks < 2; ++ks)
      #pragma unroll
      for (int mt = 0; mt < 2; ++mt)
        Af[par][ks][mt] = *(const s16x8*)(aptr[mt] + t * 64 + ks * 32);
  };

  f32x4 acc[2][2];
  #pragma unroll
  for (int mt = 0; mt < 2; ++mt)
    #pragma unroll
    for (int nt = 0; nt < 2; ++nt)
      acc[mt][nt] = (f32x4){0.f, 0.f, 0.f, 0.f};

  auto compute = [&](int t, int par) {
    const float* Bb = &Bs[t & 3][0];
    #pragma unroll
    for (int ks = 0; ks < 2; ++ks) {
      s16x8 bb[2];
      #pragma unroll
      for (int nt = 0; nt < 2; ++nt) {
        int n = wn * 32 + nt * 16 + lr;
        int g0 = ks * 8 + q * 2;
        const float* rowp = Bb + n * 64;
        float4 x0 = *(const float4*)(rowp + (((g0    ) ^ (n & 7)) << 2));
        float4 x1 = *(const float4*)(rowp + (((g0 + 1) ^ (n & 7)) << 2));
        bb[nt] = cvt8(x0, x1);
      }
      #pragma unroll
      for (int mt = 0; mt < 2; ++mt)
        #pragma unroll
        for (int nt = 0; nt < 2; ++nt)
          acc[mt][nt] = __builtin_amdgcn_mfma_f32_16x16x32_bf16(
              Af[par][ks][mt], bb[nt], acc[mt][nt], 0, 0, 0);
    }
  };

  // ---- prologue: A(0); B stages 0..2 in flight ----
  load_A(0, 0);
  stage_B(0, 0); stage_B(1, 1); stage_B(2, 2);
  __builtin_amdgcn_sched_barrier(0);

  // ---- main loop: compute(t) with A(t+1) + B(t+3) in flight ----
  for (int t = 0; t < NKT; ++t) {
    int ta = (t + 1 < NKT) ? t + 1 : NKT - 1;   // clamped tail (benign reload)
    int tb = (t + 3 < NKT) ? t + 3 : NKT - 1;   // clamped tail (same-data re-stage)
    load_A(ta, (t + 1) & 1);
    stage_B(tb, tb & 3);
    __builtin_amdgcn_sched_barrier(0);
    // outstanding: A(t+1)=4 + B(t+1..t+3)=6 -> everything older (B(t),A(t)) done
    asm volatile("s_waitcnt vmcnt(10)" ::: "memory");
    __builtin_amdgcn_s_barrier();
    __builtin_amdgcn_sched_barrier(0);
    compute(t, t & 1);
    __builtin_amdgcn_sched_barrier(0);
    __builtin_amdgcn_s_barrier();   // protect buf t&3 before re-stage at t+1
  }

  // ---- epilogue: per-row partial max / sumexp over this wave's 32 cols ----
  // C/D layout: col = lane&15, row = (lane>>4)*4 + reg
  int pb = nb * 2 + wn;
  #pragma unroll
  for (int mt = 0; mt < 2; ++mt) {
    #pragma unroll
    for (int rg = 0; rg < 4; ++rg) {
      float v0 = acc[mt][0][rg] * TEMP_INV;
      float v1 = acc[mt][1][rg] * TEMP_INV;
      float m = fmaxf(v0, v1);
      #pragma unroll
      for (int d = 1; d < 16; d <<= 1) m = fmaxf(m, __shfl_xor(m, d, 64));
      float s = __expf(v0 - m) + __expf(v1 - m);
      #pragma unroll
      for (int d = 1; d < 16; d <<= 1) s += __shfl_xor(s, d, 64);
      if ((lane & 15) == 0) {
        int row = mb * 128 + wm * 32 + mt * 16 + (lane >> 4) * 4 + rg;
        pmax[(size_t)row * NPB + pb] = m;
        psum[(size_t)row * NPB + pb] = s;
      }
    }
  }
}

// ---------------- kernel 3: parallel LSE combine (one block per row) --------
__global__ __launch_bounds__(512) void combine_kernel(
    const float* __restrict__ pmax, const float* __restrict__ psum,
    float* __restrict__ lse) {
  int row = blockIdx.x, t = threadIdx.x;
  float m = pmax[(size_t)row * NPB + t];
  float s = psum[(size_t)row * NPB + t];
  float mw = m;
  #pragma unroll
  for (int d = 1; d < 64; d <<= 1) mw = fmaxf(mw, __shfl_xor(mw, d, 64));
  __shared__ float redm[8], reds[8];
  if ((t & 63) == 0) redm[t >> 6] = mw;
  __syncthreads();
  float M = fmaxf(fmaxf(fmaxf(redm[0], redm[1]), fmaxf(redm[2], redm[3])),
                  fmaxf(fmaxf(redm[4], redm[5]), fmaxf(redm[6], redm[7])));
  float sv = s * __expf(m - M);
  #pragma unroll
  for (int d = 1; d < 64; d <<= 1) sv += __shfl_xor(sv, d, 64);
  if ((t & 63) == 0) reds[t >> 6] = sv;
  __syncthreads();
  if (t == 0) {
    float S = reds[0] + reds[1] + reds[2] + reds[3]
            + reds[4] + reds[5] + reds[6] + reds[7];
    lse[row] = M + logf(S);
  }
}

// ---------------- kernel 4: group logic -> loss -----------------------------
__global__ __launch_bounds__(256) void finish_kernel(
    const float* __restrict__ lse, const float* __restrict__ s_own,
    const int* __restrict__ targets, const int* __restrict__ cams,
    float* __restrict__ out) {
  int i = threadIdx.x;
  float mylse = lse[i];

  __shared__ float so[256]; __shared__ int tg[256], cmn[256];
  __shared__ float gfirst[256];
  so[i] = s_own[i]; tg[i] = targets[i]; cmn[i] = cams[i];
  __syncthreads();
  int ti = tg[i], ci = cmn[i]; float soi = so[i];
  float gmin = 1e30f;
  bool grp_first = true, psid_first = true;
  for (int j = 0; j < 256; ++j) {
    if (tg[j] == ti) {
      if (j < i) psid_first = false;
      if (cmn[j] == ci) {
        gmin = fminf(gmin, so[j]);
        if (j < i) grp_first = false;
      }
    }
  }
  bool ismin = (soi <= gmin);
  gfirst[i] = grp_first ? 1.f : 0.f;
  __syncthreads();
  float ngroups = 0.f; bool prior = false;
  for (int j = 0; j < 256; ++j) {
    if (tg[j] == ti) {
      ngroups += gfirst[j];
      if (j < i && cmn[j] == ci && so[j] <= gmin) prior = true;
    }
  }
  float contrib = (ismin && !prior) ? (mylse - soi) / ngroups : 0.f;
  float pf = psid_first ? 1.f : 0.f;
  #pragma unroll
  for (int d = 1; d < 64; d <<= 1) {
    contrib += __shfl_xor(contrib, d, 64);
    pf += __shfl_xor(pf, d, 64);
  }
  __shared__ float rc[4], rp[4];
  if ((i & 63) == 0) { rc[i >> 6] = contrib; rp[i >> 6] = pf; }
  __syncthreads();
  if (i == 0) out[0] = (rc[0] + rc[1] + rc[2] + rc[3]) / (rp[0] + rp[1] + rp[2] + rp[3]);
}

extern "C" void kernel_launch(void* const* d_in, const int* in_sizes, int n_in,
                              void* d_out, int out_size, void* d_ws, size_t ws_size,
                              hipStream_t stream) {
  const float* inputs  = (const float*)d_in[0];
  const float* feats   = (const float*)d_in[1];
  const int*   targets = (const int*)d_in[2];
  const int*   cams    = (const int*)d_in[3];
  float* out = (float*)d_out;
  char* ws = (char*)d_ws;
  // ws: s_own 1KB | lse 1KB | pad | pmax 512KB | psum 512KB | x_bf16 1MB
  float* s_own    = (float*)(ws + 1024);
  float* lse      = (float*)(ws + 2048);
  float* pmax     = (float*)(ws + 4096);
  float* psum     = (float*)(ws + 4096 + 512 * 1024);
  unsigned short* xb = (unsigned short*)(ws + 4096 + 1024 * 1024);

  norm_sown_kernel<<<Bn, 256, 0, stream>>>(inputs, feats, targets, xb, s_own);
  gemm_kernel<<<512, 512, 0, stream>>>(xb, feats, pmax, psum);
  combine_kernel<<<Bn, NPB, 0, stream>>>(pmax, psum, lse);
  finish_kernel<<<1, 256, 0, stream>>>(lse, s_own, targets, cams, out);
}

// Round 9
// 154.169 us; speedup vs baseline: 23.5116x; 23.5116x over previous
//
#include <hip/hip_runtime.h>

// B=256 samples, D=2048 dims, N=16384 bank rows. Dominant cost:
// sims = normalize(inputs) @ features^T / 0.05 -> per-row logsumexp.
// HBM floor: features 134 MB f32 read once ~= 21 us at 6.3 TB/s.
// ROUND 9: abandon hand-counted vmcnt pipeline (2 rounds of NaN races).
// Proven-correct m97-style structure: double-buffered B in LDS via
// global_load_lds, ONE __syncthreads per K-step (hipcc emits the full
// vmcnt drain -- safe by construction). Latency hiding comes from FOUR
// blocks per CU (grid 1024, 32 KB LDS, 256 thr) whose stalls overlap.

constexpr int Bn = 256;     // batch
constexpr int Dk = 2048;    // feature dim
constexpr int Nn = 16384;   // bank rows
constexpr int NKT = 32;     // K-steps (BK = 64 f32)
constexpr int NPB = 512;    // partial chunks (256 nb * 2 wn)
constexpr float TEMP_INV = 20.0f;

typedef float f32x4 __attribute__((ext_vector_type(4)));
typedef short s16x8 __attribute__((ext_vector_type(8)));

__device__ inline unsigned short f2bf(float f) {
  union { float f; unsigned u; } v; v.f = f;
  unsigned r = v.u + 0x7FFFu + ((v.u >> 16) & 1u);   // RNE
  return (unsigned short)(r >> 16);
}

// 8 f32 -> 8 bf16 packed, RNE, via v_cvt_pk_bf16_f32 (no builtin on gfx950)
__device__ inline s16x8 cvt8(float4 a, float4 b) {
  union { unsigned int u[4]; s16x8 v; } r;
  asm("v_cvt_pk_bf16_f32 %0, %1, %2" : "=v"(r.u[0]) : "v"(a.x), "v"(a.y));
  asm("v_cvt_pk_bf16_f32 %0, %1, %2" : "=v"(r.u[1]) : "v"(a.z), "v"(a.w));
  asm("v_cvt_pk_bf16_f32 %0, %1, %2" : "=v"(r.u[2]) : "v"(b.x), "v"(b.y));
  asm("v_cvt_pk_bf16_f32 %0, %1, %2" : "=v"(r.u[3]) : "v"(b.z), "v"(b.w));
  return r.v;
}

// ---------------- kernel 1: normalize inputs -> bf16 + exact s_own ----------
__global__ __launch_bounds__(256) void norm_sown_kernel(
    const float* __restrict__ x, const float* __restrict__ feats,
    const int* __restrict__ targets, unsigned short* __restrict__ xb,
    float* __restrict__ s_own) {
  int row = blockIdx.x, t = threadIdx.x;
  const float* xr = x + (size_t)row * Dk;
  const float* fr = feats + (size_t)targets[row] * Dk;
  float4 a  = *(const float4*)(xr + t * 8);
  float4 b  = *(const float4*)(xr + t * 8 + 4);
  float4 fa = *(const float4*)(fr + t * 8);
  float4 fb = *(const float4*)(fr + t * 8 + 4);
  float ss = a.x*a.x + a.y*a.y + a.z*a.z + a.w*a.w
           + b.x*b.x + b.y*b.y + b.z*b.z + b.w*b.w;
  float dt = a.x*fa.x + a.y*fa.y + a.z*fa.z + a.w*fa.w
           + b.x*fb.x + b.y*fb.y + b.z*fb.z + b.w*fb.w;
  #pragma unroll
  for (int d = 1; d < 64; d <<= 1) {
    ss += __shfl_xor(ss, d, 64);
    dt += __shfl_xor(dt, d, 64);
  }
  __shared__ float rs[4], rd[4];
  if ((t & 63) == 0) { rs[t >> 6] = ss; rd[t >> 6] = dt; }
  __syncthreads();
  float inv = rsqrtf(rs[0] + rs[1] + rs[2] + rs[3]);
  union { unsigned short s[8]; uint4 v; } pk;
  pk.s[0] = f2bf(a.x*inv); pk.s[1] = f2bf(a.y*inv);
  pk.s[2] = f2bf(a.z*inv); pk.s[3] = f2bf(a.w*inv);
  pk.s[4] = f2bf(b.x*inv); pk.s[5] = f2bf(b.y*inv);
  pk.s[6] = f2bf(b.z*inv); pk.s[7] = f2bf(b.w*inv);
  *(uint4*)(xb + (size_t)row * Dk + t * 8) = pk.v;
  if (t == 0) s_own[row] = (rd[0] + rd[1] + rd[2] + rd[3]) * inv * TEMP_INV;
}

// ---------------- kernel 2: double-buffered GEMM + partial LSE --------------
// grid 1024: mb = bid>>8 in [0,4) -> 64 rows; nb = bid&255 -> 64 cols.
// 256 threads, 4 waves: wm = w>>1 -> 32 rows, wn = w&1 -> 32 cols.
// One __syncthreads per K-step; stalls overlap across 4 blocks/CU.
__global__ __launch_bounds__(256, 4) void gemm_kernel(
    const unsigned short* __restrict__ xb, const float* __restrict__ feats,
    float* __restrict__ pmax, float* __restrict__ psum) {
  __shared__ float Bs[2][64 * 64];   // 2 x 16 KB f32 tiles

  int tid = threadIdx.x;
  int w = tid >> 6, lane = tid & 63;
  int wm = w >> 1, wn = w & 1;
  int bid = blockIdx.x;
  int mb = bid >> 8, nb = bid & 255;
  int n0 = nb * 64;
  int lr = lane & 15, q = lane >> 4;

  // B staging: slot s = w*4+j (16 slots x 1 KB). Lane l writes bytes
  // [s*1024 + l*16): row = s*4 + (l>>4), stored pos = l&15. Source is
  // granule g = pos ^ (row&7)  (XOR swizzle; inverse == same XOR).
  auto stage_B = [&](int kt, int buf) {
    int k0 = kt * 64;
    #pragma unroll
    for (int j = 0; j < 4; ++j) {
      int s = w * 4 + j;
      int row = s * 4 + q;
      int g = lr ^ (row & 7);
      const float* src = feats + (size_t)(n0 + row) * Dk + k0 + g * 4;
      __builtin_amdgcn_global_load_lds(
          (const __attribute__((address_space(1))) unsigned int*)src,
          (__attribute__((address_space(3))) unsigned int*)
              ((unsigned char*)&Bs[buf][0] + s * 1024),
          16, 0, 0);
    }
  };

  // A: direct per-wave global fragment loads (xb is 1 MB, L2-hot)
  const unsigned short* aptr[2];
  #pragma unroll
  for (int mt = 0; mt < 2; ++mt)
    aptr[mt] = xb + (size_t)(mb * 64 + wm * 32 + mt * 16 + lr) * Dk + q * 8;

  f32x4 acc[2][2];
  #pragma unroll
  for (int mt = 0; mt < 2; ++mt)
    #pragma unroll
    for (int nt = 0; nt < 2; ++nt)
      acc[mt][nt] = (f32x4){0.f, 0.f, 0.f, 0.f};

  stage_B(0, 0);
  __syncthreads();            // drain: B(0) fully in LDS

  for (int t = 0; t < NKT; ++t) {
    if (t + 1 < NKT) stage_B(t + 1, (t + 1) & 1);  // uniform branch; other buf
    // A fragments for this step (compiler inserts the reg waits)
    s16x8 Af[2][2];
    #pragma unroll
    for (int ks = 0; ks < 2; ++ks)
      #pragma unroll
      for (int mt = 0; mt < 2; ++mt)
        Af[ks][mt] = *(const s16x8*)(aptr[mt] + t * 64 + ks * 32);
    const float* Bb = &Bs[t & 1][0];
    #pragma unroll
    for (int ks = 0; ks < 2; ++ks) {
      s16x8 bb[2];
      #pragma unroll
      for (int nt = 0; nt < 2; ++nt) {
        int n = wn * 32 + nt * 16 + lr;
        int g0 = ks * 8 + q * 2;
        const float* rowp = Bb + n * 64;
        float4 x0 = *(const float4*)(rowp + (((g0    ) ^ (n & 7)) << 2));
        float4 x1 = *(const float4*)(rowp + (((g0 + 1) ^ (n & 7)) << 2));
        bb[nt] = cvt8(x0, x1);
      }
      #pragma unroll
      for (int mt = 0; mt < 2; ++mt)
        #pragma unroll
        for (int nt = 0; nt < 2; ++nt)
          acc[mt][nt] = __builtin_amdgcn_mfma_f32_16x16x32_bf16(
              Af[ks][mt], bb[nt], acc[mt][nt], 0, 0, 0);
    }
    // Single sync: drains vmcnt(0) (B(t+1) landed) and protects buf t&1
    // from being re-staged at t+1 before all waves finished reading it.
    __syncthreads();
  }

  // ---- epilogue: per-row partial max / sumexp over this wave's 32 cols ----
  // C/D layout: col = lane&15, row = (lane>>4)*4 + reg
  int pb = nb * 2 + wn;
  #pragma unroll
  for (int mt = 0; mt < 2; ++mt) {
    #pragma unroll
    for (int rg = 0; rg < 4; ++rg) {
      float v0 = acc[mt][0][rg] * TEMP_INV;
      float v1 = acc[mt][1][rg] * TEMP_INV;
      float m = fmaxf(v0, v1);
      #pragma unroll
      for (int d = 1; d < 16; d <<= 1) m = fmaxf(m, __shfl_xor(m, d, 64));
      float s = __expf(v0 - m) + __expf(v1 - m);
      #pragma unroll
      for (int d = 1; d < 16; d <<= 1) s += __shfl_xor(s, d, 64);
      if ((lane & 15) == 0) {
        int row = mb * 64 + wm * 32 + mt * 16 + (lane >> 4) * 4 + rg;
        pmax[(size_t)row * NPB + pb] = m;
        psum[(size_t)row * NPB + pb] = s;
      }
    }
  }
}

// ---------------- kernel 3: parallel LSE combine (one block per row) --------
__global__ __launch_bounds__(512) void combine_kernel(
    const float* __restrict__ pmax, const float* __restrict__ psum,
    float* __restrict__ lse) {
  int row = blockIdx.x, t = threadIdx.x;
  float m = pmax[(size_t)row * NPB + t];
  float s = psum[(size_t)row * NPB + t];
  float mw = m;
  #pragma unroll
  for (int d = 1; d < 64; d <<= 1) mw = fmaxf(mw, __shfl_xor(mw, d, 64));
  __shared__ float redm[8], reds[8];
  if ((t & 63) == 0) redm[t >> 6] = mw;
  __syncthreads();
  float M = fmaxf(fmaxf(fmaxf(redm[0], redm[1]), fmaxf(redm[2], redm[3])),
                  fmaxf(fmaxf(redm[4], redm[5]), fmaxf(redm[6], redm[7])));
  float sv = s * __expf(m - M);
  #pragma unroll
  for (int d = 1; d < 64; d <<= 1) sv += __shfl_xor(sv, d, 64);
  if ((t & 63) == 0) reds[t >> 6] = sv;
  __syncthreads();
  if (t == 0) {
    float S = reds[0] + reds[1] + reds[2] + reds[3]
            + reds[4] + reds[5] + reds[6] + reds[7];
    lse[row] = M + logf(S);
  }
}

// ---------------- kernel 4: group logic -> loss -----------------------------
__global__ __launch_bounds__(256) void finish_kernel(
    const float* __restrict__ lse, const float* __restrict__ s_own,
    const int* __restrict__ targets, const int* __restrict__ cams,
    float* __restrict__ out) {
  int i = threadIdx.x;
  float mylse = lse[i];

  __shared__ float so[256]; __shared__ int tg[256], cmn[256];
  __shared__ float gfirst[256];
  so[i] = s_own[i]; tg[i] = targets[i]; cmn[i] = cams[i];
  __syncthreads();
  int ti = tg[i], ci = cmn[i]; float soi = so[i];
  float gmin = 1e30f;
  bool grp_first = true, psid_first = true;
  for (int j = 0; j < 256; ++j) {
    if (tg[j] == ti) {
      if (j < i) psid_first = false;
      if (cmn[j] == ci) {
        gmin = fminf(gmin, so[j]);
        if (j < i) grp_first = false;
      }
    }
  }
  bool ismin = (soi <= gmin);
  gfirst[i] = grp_first ? 1.f : 0.f;
  __syncthreads();
  float ngroups = 0.f; bool prior = false;
  for (int j = 0; j < 256; ++j) {
    if (tg[j] == ti) {
      ngroups += gfirst[j];
      if (j < i && cmn[j] == ci && so[j] <= gmin) prior = true;
    }
  }
  float contrib = (ismin && !prior) ? (mylse - soi) / ngroups : 0.f;
  float pf = psid_first ? 1.f : 0.f;
  #pragma unroll
  for (int d = 1; d < 64; d <<= 1) {
    contrib += __shfl_xor(contrib, d, 64);
    pf += __shfl_xor(pf, d, 64);
  }
  __shared__ float rc[4], rp[4];
  if ((i & 63) == 0) { rc[i >> 6] = contrib; rp[i >> 6] = pf; }
  __syncthreads();
  if (i == 0) out[0] = (rc[0] + rc[1] + rc[2] + rc[3]) / (rp[0] + rp[1] + rp[2] + rp[3]);
}

extern "C" void kernel_launch(void* const* d_in, const int* in_sizes, int n_in,
                              void* d_out, int out_size, void* d_ws, size_t ws_size,
                              hipStream_t stream) {
  const float* inputs  = (const float*)d_in[0];
  const float* feats   = (const float*)d_in[1];
  const int*   targets = (const int*)d_in[2];
  const int*   cams    = (const int*)d_in[3];
  float* out = (float*)d_out;
  char* ws = (char*)d_ws;
  // ws: s_own 1KB | lse 1KB | pad | pmax 512KB | psum 512KB | x_bf16 1MB
  float* s_own    = (float*)(ws + 1024);
  float* lse      = (float*)(ws + 2048);
  float* pmax     = (float*)(ws + 4096);
  float* psum     = (float*)(ws + 4096 + 512 * 1024);
  unsigned short* xb = (unsigned short*)(ws + 4096 + 1024 * 1024);

  norm_sown_kernel<<<Bn, 256, 0, stream>>>(inputs, feats, targets, xb, s_own);
  gemm_kernel<<<1024, 256, 0, stream>>>(xb, feats, pmax, psum);
  combine_kernel<<<Bn, NPB, 0, stream>>>(pmax, psum, lse);
  finish_kernel<<<1, 256, 0, stream>>>(lse, s_own, targets, cams, out);
}

// Round 10
// 150.871 us; speedup vs baseline: 24.0256x; 1.0219x over previous
//
#include <hip/hip_runtime.h>

// B=256 samples, D=2048 dims, N=16384 bank rows. Dominant cost:
// sims = normalize(inputs) @ features^T / 0.05 -> per-row logsumexp.
// HBM floor: features 134 MB f32 read once ~= 21 us at 6.3 TB/s.
// ROUND 10: round 9 was correct but HBM ran at 2 TB/s: 1024 blocks x 32
// steps of 256B-chunk reads (page thrash) + 4x B re-read (mb split) +
// zero-depth pipeline (syncthreads drains the just-issued stage).
// Fix: grid 256, block = ALL 256 rows x 64-col panel (B read ONCE),
// BK=256 f32 (1 KB contiguous per row per stage, 8 steps), 2x64 KB LDS
// double buffer, one __syncthreads per step (safe-by-construction sync;
// transfer 2.6 us/step dwarfs the drained latency).

constexpr int Bn = 256;     // batch
constexpr int Dk = 2048;    // feature dim
constexpr int Nn = 16384;   // bank rows
constexpr int BKf = 256;    // f32 per K-step
constexpr int NKT = Dk / BKf; // 8
constexpr int NPB = 512;    // partial chunks (256 nb * 2 wn)
constexpr float TEMP_INV = 20.0f;

typedef float f32x4 __attribute__((ext_vector_type(4)));
typedef short s16x8 __attribute__((ext_vector_type(8)));

__device__ inline unsigned short f2bf(float f) {
  union { float f; unsigned u; } v; v.f = f;
  unsigned r = v.u + 0x7FFFu + ((v.u >> 16) & 1u);   // RNE
  return (unsigned short)(r >> 16);
}

// 8 f32 -> 8 bf16 packed, RNE, via v_cvt_pk_bf16_f32 (no builtin on gfx950)
__device__ inline s16x8 cvt8(float4 a, float4 b) {
  union { unsigned int u[4]; s16x8 v; } r;
  asm("v_cvt_pk_bf16_f32 %0, %1, %2" : "=v"(r.u[0]) : "v"(a.x), "v"(a.y));
  asm("v_cvt_pk_bf16_f32 %0, %1, %2" : "=v"(r.u[1]) : "v"(a.z), "v"(a.w));
  asm("v_cvt_pk_bf16_f32 %0, %1, %2" : "=v"(r.u[2]) : "v"(b.x), "v"(b.y));
  asm("v_cvt_pk_bf16_f32 %0, %1, %2" : "=v"(r.u[3]) : "v"(b.z), "v"(b.w));
  return r.v;
}

// ---------------- kernel 1: normalize inputs -> bf16 + exact s_own ----------
__global__ __launch_bounds__(256) void norm_sown_kernel(
    const float* __restrict__ x, const float* __restrict__ feats,
    const int* __restrict__ targets, unsigned short* __restrict__ xb,
    float* __restrict__ s_own) {
  int row = blockIdx.x, t = threadIdx.x;
  const float* xr = x + (size_t)row * Dk;
  const float* fr = feats + (size_t)targets[row] * Dk;
  float4 a  = *(const float4*)(xr + t * 8);
  float4 b  = *(const float4*)(xr + t * 8 + 4);
  float4 fa = *(const float4*)(fr + t * 8);
  float4 fb = *(const float4*)(fr + t * 8 + 4);
  float ss = a.x*a.x + a.y*a.y + a.z*a.z + a.w*a.w
           + b.x*b.x + b.y*b.y + b.z*b.z + b.w*b.w;
  float dt = a.x*fa.x + a.y*fa.y + a.z*fa.z + a.w*fa.w
           + b.x*fb.x + b.y*fb.y + b.z*fb.z + b.w*fb.w;
  #pragma unroll
  for (int d = 1; d < 64; d <<= 1) {
    ss += __shfl_xor(ss, d, 64);
    dt += __shfl_xor(dt, d, 64);
  }
  __shared__ float rs[4], rd[4];
  if ((t & 63) == 0) { rs[t >> 6] = ss; rd[t >> 6] = dt; }
  __syncthreads();
  float inv = rsqrtf(rs[0] + rs[1] + rs[2] + rs[3]);
  union { unsigned short s[8]; uint4 v; } pk;
  pk.s[0] = f2bf(a.x*inv); pk.s[1] = f2bf(a.y*inv);
  pk.s[2] = f2bf(a.z*inv); pk.s[3] = f2bf(a.w*inv);
  pk.s[4] = f2bf(b.x*inv); pk.s[5] = f2bf(b.y*inv);
  pk.s[6] = f2bf(b.z*inv); pk.s[7] = f2bf(b.w*inv);
  *(uint4*)(xb + (size_t)row * Dk + t * 8) = pk.v;
  if (t == 0) s_own[row] = (rd[0] + rd[1] + rd[2] + rd[3]) * inv * TEMP_INV;
}

// ---------------- kernel 2: read-once coarse-stream GEMM + partial LSE ------
// grid 256 (one 64-col B panel each), 512 threads = 8 waves:
// wm = w>>1 in [0,4) -> 64 rows (mt x4); wn = w&1 -> 32 cols (nt x2).
__global__ __launch_bounds__(512, 2) void gemm_kernel(
    const unsigned short* __restrict__ xb, const float* __restrict__ feats,
    float* __restrict__ pmax, float* __restrict__ psum) {
  __shared__ float Bs[2][64 * BKf];   // 2 x 64 KB f32 tiles (128 KB)

  int tid = threadIdx.x;
  int w = tid >> 6, lane = tid & 63;
  int wm = w >> 1, wn = w & 1;
  int nb = blockIdx.x;
  int n0 = nb * 64;
  int lr = lane & 15, q = lane >> 4;

  // B staging: wave w, j in [0,8) -> row = j*8 + w (1 KB contiguous).
  // Lane l fetches source granule (l ^ w) -> HW stores at pos l, so
  // stored pos p holds granule p ^ (row&7)  [row&7 == w]. Read side
  // uses the same XOR (involution).
  auto stage_B = [&](int kt, int buf) {
    const float* base = feats + (size_t)n0 * Dk + kt * BKf + ((lane ^ w) << 2);
    #pragma unroll
    for (int j = 0; j < 8; ++j) {
      int row = j * 8 + w;
      __builtin_amdgcn_global_load_lds(
          (const __attribute__((address_space(1))) unsigned int*)
              (base + (size_t)row * Dk),
          (__attribute__((address_space(3))) unsigned int*)
              ((unsigned char*)&Bs[buf][0] + row * 1024),
          16, 0, 0);
    }
  };

  // A: direct per-wave global fragment loads (xb is 1 MB, L1/L2-hot)
  const unsigned short* aptr[4];
  #pragma unroll
  for (int mt = 0; mt < 4; ++mt)
    aptr[mt] = xb + (size_t)(wm * 64 + mt * 16 + lr) * Dk + q * 8;

  f32x4 acc[4][2];
  #pragma unroll
  for (int mt = 0; mt < 4; ++mt)
    #pragma unroll
    for (int nt = 0; nt < 2; ++nt)
      acc[mt][nt] = (f32x4){0.f, 0.f, 0.f, 0.f};

  stage_B(0, 0);
  __syncthreads();            // drain: B(0) fully in LDS

  for (int t = 0; t < NKT; ++t) {
    if (t + 1 < NKT) stage_B(t + 1, (t + 1) & 1);  // other buffer
    const float* Bb = &Bs[t & 1][0];
    #pragma unroll
    for (int ks = 0; ks < 8; ++ks) {
      s16x8 Af[4];
      #pragma unroll
      for (int mt = 0; mt < 4; ++mt)
        Af[mt] = *(const s16x8*)(aptr[mt] + t * BKf + ks * 32);
      s16x8 bb[2];
      #pragma unroll
      for (int nt = 0; nt < 2; ++nt) {
        int n = wn * 32 + nt * 16 + lr;
        int g0 = ks * 8 + q * 2;
        const float* rowp = Bb + n * BKf;
        float4 x0 = *(const float4*)(rowp + (((g0    ) ^ (n & 7)) << 2));
        float4 x1 = *(const float4*)(rowp + (((g0 + 1) ^ (n & 7)) << 2));
        bb[nt] = cvt8(x0, x1);
      }
      #pragma unroll
      for (int mt = 0; mt < 4; ++mt)
        #pragma unroll
        for (int nt = 0; nt < 2; ++nt)
          acc[mt][nt] = __builtin_amdgcn_mfma_f32_16x16x32_bf16(
              Af[mt], bb[nt], acc[mt][nt], 0, 0, 0);
    }
    // Single sync: drains vmcnt (B(t+1) landed) and protects buf t&1
    // from re-stage at t+1 before all waves finished reading it.
    __syncthreads();
  }

  // ---- epilogue: per-row partial max / sumexp over this wave's 32 cols ----
  // C/D layout: col = lane&15, row = (lane>>4)*4 + reg
  int pb = nb * 2 + wn;
  #pragma unroll
  for (int mt = 0; mt < 4; ++mt) {
    #pragma unroll
    for (int rg = 0; rg < 4; ++rg) {
      float v0 = acc[mt][0][rg] * TEMP_INV;
      float v1 = acc[mt][1][rg] * TEMP_INV;
      float m = fmaxf(v0, v1);
      #pragma unroll
      for (int d = 1; d < 16; d <<= 1) m = fmaxf(m, __shfl_xor(m, d, 64));
      float s = __expf(v0 - m) + __expf(v1 - m);
      #pragma unroll
      for (int d = 1; d < 16; d <<= 1) s += __shfl_xor(s, d, 64);
      if ((lane & 15) == 0) {
        int row = wm * 64 + mt * 16 + (lane >> 4) * 4 + rg;
        pmax[(size_t)row * NPB + pb] = m;
        psum[(size_t)row * NPB + pb] = s;
      }
    }
  }
}

// ---------------- kernel 3: parallel LSE combine (one block per row) --------
__global__ __launch_bounds__(512) void combine_kernel(
    const float* __restrict__ pmax, const float* __restrict__ psum,
    float* __restrict__ lse) {
  int row = blockIdx.x, t = threadIdx.x;
  float m = pmax[(size_t)row * NPB + t];
  float s = psum[(size_t)row * NPB + t];
  float mw = m;
  #pragma unroll
  for (int d = 1; d < 64; d <<= 1) mw = fmaxf(mw, __shfl_xor(mw, d, 64));
  __shared__ float redm[8], reds[8];
  if ((t & 63) == 0) redm[t >> 6] = mw;
  __syncthreads();
  float M = fmaxf(fmaxf(fmaxf(redm[0], redm[1]), fmaxf(redm[2], redm[3])),
                  fmaxf(fmaxf(redm[4], redm[5]), fmaxf(redm[6], redm[7])));
  float sv = s * __expf(m - M);
  #pragma unroll
  for (int d = 1; d < 64; d <<= 1) sv += __shfl_xor(sv, d, 64);
  if ((t & 63) == 0) reds[t >> 6] = sv;
  __syncthreads();
  if (t == 0) {
    float S = reds[0] + reds[1] + reds[2] + reds[3]
            + reds[4] + reds[5] + reds[6] + reds[7];
    lse[row] = M + logf(S);
  }
}

// ---------------- kernel 4: group logic -> loss -----------------------------
__global__ __launch_bounds__(256) void finish_kernel(
    const float* __restrict__ lse, const float* __restrict__ s_own,
    const int* __restrict__ targets, const int* __restrict__ cams,
    float* __restrict__ out) {
  int i = threadIdx.x;
  float mylse = lse[i];

  __shared__ float so[256]; __shared__ int tg[256], cmn[256];
  __shared__ float gfirst[256];
  so[i] = s_own[i]; tg[i] = targets[i]; cmn[i] = cams[i];
  __syncthreads();
  int ti = tg[i], ci = cmn[i]; float soi = so[i];
  float gmin = 1e30f;
  bool grp_first = true, psid_first = true;
  for (int j = 0; j < 256; ++j) {
    if (tg[j] == ti) {
      if (j < i) psid_first = false;
      if (cmn[j] == ci) {
        gmin = fminf(gmin, so[j]);
        if (j < i) grp_first = false;
      }
    }
  }
  bool ismin = (soi <= gmin);
  gfirst[i] = grp_first ? 1.f : 0.f;
  __syncthreads();
  float ngroups = 0.f; bool prior = false;
  for (int j = 0; j < 256; ++j) {
    if (tg[j] == ti) {
      ngroups += gfirst[j];
      if (j < i && cmn[j] == ci && so[j] <= gmin) prior = true;
    }
  }
  float contrib = (ismin && !prior) ? (mylse - soi) / ngroups : 0.f;
  float pf = psid_first ? 1.f : 0.f;
  #pragma unroll
  for (int d = 1; d < 64; d <<= 1) {
    contrib += __shfl_xor(contrib, d, 64);
    pf += __shfl_xor(pf, d, 64);
  }
  __shared__ float rc[4], rp[4];
  if ((i & 63) == 0) { rc[i >> 6] = contrib; rp[i >> 6] = pf; }
  __syncthreads();
  if (i == 0) out[0] = (rc[0] + rc[1] + rc[2] + rc[3]) / (rp[0] + rp[1] + rp[2] + rp[3]);
}

extern "C" void kernel_launch(void* const* d_in, const int* in_sizes, int n_in,
                              void* d_out, int out_size, void* d_ws, size_t ws_size,
                              hipStream_t stream) {
  const float* inputs  = (const float*)d_in[0];
  const float* feats   = (const float*)d_in[1];
  const int*   targets = (const int*)d_in[2];
  const int*   cams    = (const int*)d_in[3];
  float* out = (float*)d_out;
  char* ws = (char*)d_ws;
  // ws: s_own 1KB | lse 1KB | pad | pmax 512KB | psum 512KB | x_bf16 1MB
  float* s_own    = (float*)(ws + 1024);
  float* lse      = (float*)(ws + 2048);
  float* pmax     = (float*)(ws + 4096);
  float* psum     = (float*)(ws + 4096 + 512 * 1024);
  unsigned short* xb = (unsigned short*)(ws + 4096 + 1024 * 1024);

  norm_sown_kernel<<<Bn, 256, 0, stream>>>(inputs, feats, targets, xb, s_own);
  gemm_kernel<<<Nn / 64, 512, 0, stream>>>(xb, feats, pmax, psum);
  combine_kernel<<<Bn, NPB, 0, stream>>>(pmax, psum, lse);
  finish_kernel<<<1, 256, 0, stream>>>(lse, s_own, targets, cams, out);
}